// Round 5
// baseline (197.255 us; speedup 1.0000x reference)
//
#include <hip/hip_runtime.h>
#include <cstdint>
#include <cstddef>

// ---------------------------------------------------------------------------
// LSTM cell, B=8192, D=H=512, fp32 in/out.
// pre = [x|h] @ Wstack^T + bias ; gates -> c_t, h_t fused in GEMM epilogue.
// Round 8: REGISTER-DIRECT GEMM, no LDS, no barriers in the K-loop.
// Rationale: operands are L2-resident (A-panel 256KB shared by 16 same-XCD
// blocks; B total 4MB), so LDS staging + block-wide barrier lockstep was
// pure overhead (guide common-mistake #7). A and B are pre-packed into a
// chunk-major fragment layout [t16][kt][chunk8][row16][16B] so every MFMA
// fragment load is one fully-coalesced 1KB global_load_dwordx4 per wave,
// loaded straight to VGPRs, ping-pong prefetched one K-step ahead.
// Tile 128x128, 256 thr (4 waves, 2Mx2N, 64x64 wave tiles), grid (64,16):
// bid%8 = x%8 so all 16 blocks sharing an A-panel live on one XCD's L2.
// B rows gate-interleaved (n = h*4+gate) for the fused float4 epilogue.
// ---------------------------------------------------------------------------

typedef __attribute__((ext_vector_type(8))) short short8;   // 8 bf16 = 4 VGPRs
typedef __attribute__((ext_vector_type(4))) float floatx4;  // MFMA acc

__device__ __forceinline__ unsigned short f2bf(float f) {
  union { float f; unsigned u; } v; v.f = f;
  unsigned u = v.u;
  return (unsigned short)((u + 0x7fffu + ((u >> 16) & 1u)) >> 16);  // RNE
}

// --------------------------- pack to fragment layout -----------------------
// A' group g (write-linear): r=g&15, c=(g>>4)&7, kt=(g>>7)&15, mt=g>>11.
//   holds bf16 of A[mt*16+r][kt*64 + c*8 .. +7]   (A = [x|h] concat)
// B' same with nt; n = nt*16+r, gate = n&3, hh = n>>2 (h-interleaved).
// bias[n] = bx+bh written by the (kt==0,c==0) thread.
struct PackArgs {
  const float* x; const float* h;
  const float* wx[4]; const float* wh[4];
  const float* bx[4]; const float* bh[4];
  unsigned short* A; unsigned short* B; float* bias;
};

__global__ __launch_bounds__(256) void pack_kernel(PackArgs P) {
  const int gid = blockIdx.x * 256 + threadIdx.x;
  if (blockIdx.x < 4096) {                       // ---- A: 1M groups ----
    int g  = gid;
    int r  = g & 15, c = (g >> 4) & 7, kt = (g >> 7) & 15, mt = g >> 11;
    int m  = mt * 16 + r;
    int k  = kt * 64 + c * 8;
    const float* src = (k < 512) ? (P.x + m * 512 + k)
                                 : (P.h + m * 512 + (k - 512));
    float4 v0 = ((const float4*)src)[0];
    float4 v1 = ((const float4*)src)[1];
    union { unsigned short us[8]; short8 s; } o;
    o.us[0] = f2bf(v0.x); o.us[1] = f2bf(v0.y);
    o.us[2] = f2bf(v0.z); o.us[3] = f2bf(v0.w);
    o.us[4] = f2bf(v1.x); o.us[5] = f2bf(v1.y);
    o.us[6] = f2bf(v1.z); o.us[7] = f2bf(v1.w);
    *(short8*)(P.A + (size_t)g * 8) = o.s;
  } else {                                       // ---- B: 256K groups ----
    int g  = gid - 4096 * 256;
    int r  = g & 15, c = (g >> 4) & 7, kt = (g >> 7) & 15, nt = g >> 11;
    int n  = nt * 16 + r;
    int gate = n & 3, hh = n >> 2;
    int k  = kt * 64 + c * 8;
    const float* src = (k < 512) ? (P.wx[gate] + hh * 512 + k)
                                 : (P.wh[gate] + hh * 512 + (k - 512));
    float4 v0 = ((const float4*)src)[0];
    float4 v1 = ((const float4*)src)[1];
    union { unsigned short us[8]; short8 s; } o;
    o.us[0] = f2bf(v0.x); o.us[1] = f2bf(v0.y);
    o.us[2] = f2bf(v0.z); o.us[3] = f2bf(v0.w);
    o.us[4] = f2bf(v1.x); o.us[5] = f2bf(v1.y);
    o.us[6] = f2bf(v1.z); o.us[7] = f2bf(v1.w);
    *(short8*)(P.B + (size_t)g * 8) = o.s;
    if (kt == 0 && c == 0) P.bias[n] = P.bx[gate][hh] + P.bh[gate][hh];
  }
}

// --------------------------- fused GEMM + LSTM epilogue --------------------
// A' blocked: (mt,kt) 2KB block at ((mt*16)+kt)*1024 ushorts; within block
// lane (quad,colA) chunk kk reads offset (kk*4+quad)*128 + colA*8 ushorts
// = fully contiguous 1KB per wave-load.
#define LOADK(AF, BF, KT) do {                                            \
    _Pragma("unroll")                                                     \
    for (int mi_ = 0; mi_ < 4; ++mi_) {                                   \
      AF[mi_][0] = *(const short8*)(Aw + mi_ * 16384 + (KT) * 1024 + loff);        \
      AF[mi_][1] = *(const short8*)(Aw + mi_ * 16384 + (KT) * 1024 + 512 + loff);  \
    }                                                                     \
    _Pragma("unroll")                                                     \
    for (int ni_ = 0; ni_ < 4; ++ni_) {                                   \
      BF[ni_][0] = *(const short8*)(Bw + ni_ * 16384 + (KT) * 1024 + loff);        \
      BF[ni_][1] = *(const short8*)(Bw + ni_ * 16384 + (KT) * 1024 + 512 + loff);  \
    }                                                                     \
  } while (0)

#define MFMA_ALL(AF, BF) do {                                             \
    _Pragma("unroll")                                                     \
    for (int mi_ = 0; mi_ < 4; ++mi_)                                     \
      _Pragma("unroll")                                                   \
      for (int ni_ = 0; ni_ < 4; ++ni_)                                   \
        _Pragma("unroll")                                                 \
        for (int kk_ = 0; kk_ < 2; ++kk_)                                 \
          acc[mi_][ni_] = __builtin_amdgcn_mfma_f32_16x16x32_bf16(        \
              AF[mi_][kk_], BF[ni_][kk_], acc[mi_][ni_], 0, 0, 0);        \
  } while (0)

__global__ __launch_bounds__(256, 2)
void lstm_gemm_kernel(const unsigned short* __restrict__ A,   // frag-blocked
                      const unsigned short* __restrict__ B,   // frag-blocked
                      const float* __restrict__ bias,         // [2048]
                      const float* __restrict__ c_prev,       // [8192][512]
                      float* __restrict__ h_out,              // [8192][512]
                      float* __restrict__ c_out) {            // [8192][512]
  __shared__ __align__(16) float ep[64 * 132];   // conflict-free epilogue
  __shared__ __align__(16) float biasS[128];

  const int tid  = threadIdx.x;
  const int lane = tid & 63;
  const int w    = tid >> 6;        // wave 0..3
  const int quad = lane >> 4;
  const int colA = lane & 15;
  const int m0   = blockIdx.x * 128;
  const int n0   = blockIdx.y * 128;
  const int h0   = blockIdx.y * 32;

  if (tid < 128) biasS[tid] = bias[n0 + tid];

  const int wm = (w >> 1) * 64;
  const int wn = (w & 1) * 64;

  const unsigned short* Aw = A + (size_t)(blockIdx.x * 8 + (w >> 1) * 4) * 16384;
  const unsigned short* Bw = B + (size_t)(blockIdx.y * 8 + (w & 1) * 4) * 16384;
  const int loff = quad * 128 + colA * 8;        // ushort offset within block

  floatx4 acc[4][4];
#pragma unroll
  for (int i = 0; i < 4; ++i)
#pragma unroll
    for (int j = 0; j < 4; ++j) acc[i][j] = (floatx4){0.f, 0.f, 0.f, 0.f};

  short8 a0[4][2], b0[4][2], a1[4][2], b1[4][2];
  LOADK(a0, b0, 0);
#pragma unroll
  for (int kt = 0; kt < 16; kt += 2) {
    LOADK(a1, b1, kt + 1);          // prefetch odd step
    MFMA_ALL(a0, b0);               // compute even step
    if (kt + 2 < 16) LOADK(a0, b0, kt + 2);
    MFMA_ALL(a1, b1);
  }

  // ------------------- fused epilogue (2 rounds of 64 M-rows) --------------
  __syncthreads();
#pragma unroll
  for (int rd = 0; rd < 2; ++rd) {
    float cp[8];
#pragma unroll
    for (int j = 0; j < 8; ++j) {
      int idx  = j * 256 + tid;     // 0..2047
      int mloc = idx >> 5;
      int hh   = idx & 31;
      cp[j] = c_prev[(m0 + rd * 64 + mloc) * 512 + h0 + hh];
    }
    if ((w >> 1) == rd) {           // the 2 waves with wm == rd*64
      // C/D layout: row = quad*4 + rr, col = lane&15
#pragma unroll
      for (int mi = 0; mi < 4; ++mi)
#pragma unroll
        for (int ni = 0; ni < 4; ++ni) {
          int rr0 = mi * 16 + quad * 4;                 // local row 0..63
          int cc  = wn + ni * 16 + colA;                // col 0..127
#pragma unroll
          for (int rr = 0; rr < 4; ++rr)
            ep[(rr0 + rr) * 132 + cc] = acc[mi][ni][rr];
        }
    }
    __syncthreads();
#pragma unroll
    for (int j = 0; j < 8; ++j) {
      int idx  = j * 256 + tid;     // 0..2047
      int mloc = idx >> 5;
      int hh   = idx & 31;
      // one aligned float4 = (f,i,g,o) pre-activations for this (m,h)
      float4 pre = *(const float4*)(ep + mloc * 132 + hh * 4);
      float4 bb  = *(const float4*)(biasS + hh * 4);
      float pf = pre.x + bb.x;
      float pi = pre.y + bb.y;
      float pg = pre.z + bb.z;
      float po = pre.w + bb.w;
      float fg = 1.f / (1.f + __expf(-pf));
      float ig = 1.f / (1.f + __expf(-pi));
      float gg = 1.f - 2.f / (1.f + __expf(2.f * pg));
      float og = 1.f / (1.f + __expf(-po));
      float cv = fg * cp[j] + ig * gg;
      float th = 1.f - 2.f / (1.f + __expf(2.f * cv));
      int m  = m0 + rd * 64 + mloc;
      int hg = h0 + hh;
      h_out[m * 512 + hg] = og * th;
      c_out[m * 512 + hg] = cv;
    }
    __syncthreads();
  }
}

// ---------------------------------------------------------------------------
extern "C" void kernel_launch(void* const* d_in, const int* in_sizes, int n_in,
                              void* d_out, int out_size, void* d_ws, size_t ws_size,
                              hipStream_t stream) {
  // workspace: A' bf16 (16 MiB) | B' bf16 (4 MiB) | bias (8 KiB)
  char* ws = (char*)d_ws;
  unsigned short* Abf = (unsigned short*)ws;
  unsigned short* Bbf = (unsigned short*)(ws + (size_t)16777216);
  float* bias = (float*)(ws + (size_t)16777216 + 4194304);

  float* hout = (float*)d_out;
  float* cout = hout + (size_t)8192 * 512;

  PackArgs P;
  P.x = (const float*)d_in[0];
  P.h = (const float*)d_in[1];
  // gate order: 0=f, 1=i, 2=g(cell), 3=o
  P.wx[0] = (const float*)d_in[3];  P.bx[0] = (const float*)d_in[4];
  P.wh[0] = (const float*)d_in[5];  P.bh[0] = (const float*)d_in[6];
  P.wx[1] = (const float*)d_in[7];  P.bx[1] = (const float*)d_in[8];
  P.wh[1] = (const float*)d_in[9];  P.bh[1] = (const float*)d_in[10];
  P.wx[2] = (const float*)d_in[11]; P.bx[2] = (const float*)d_in[12];
  P.wh[2] = (const float*)d_in[13]; P.bh[2] = (const float*)d_in[14];
  P.wx[3] = (const float*)d_in[15]; P.bx[3] = (const float*)d_in[16];
  P.wh[3] = (const float*)d_in[17]; P.bh[3] = (const float*)d_in[18];
  P.A = Abf; P.B = Bbf; P.bias = bias;

  pack_kernel<<<5120, 256, 0, stream>>>(P);

  const float* c = (const float*)d_in[2];
  dim3 grid(64, 16);
  lstm_gemm_kernel<<<grid, 256, 0, stream>>>(Abf, Bbf, bias, c, hout, cout);
}

// Round 6
// 167.245 us; speedup vs baseline: 1.1794x; 1.1794x over previous
//
#include <hip/hip_runtime.h>
#include <cstdint>
#include <cstddef>

// ---------------------------------------------------------------------------
// LSTM cell, B=8192, D=H=512, fp32 in/out.
// pre = [x|h] @ Wstack^T + bias ; gates -> c_t, h_t fused in GEMM epilogue.
// Round 9: champion r0 structure (256x128 tile, 2 blk/CU, 48us GEMM) with
// the three r6-proven epilogue grafts only -- K-loop untouched:
//  (1) B packed h-interleaved (row n = 4h+gate) so each cell's (f,i,g,o)
//      is ONE aligned float4 in LDS (replaces 8 scalar LDS reads/cell),
//  (2) c_prev loads hoisted before the ep-publish barrier (latency hidden),
//  (3) bias as float4.
// Structural escapes (8-phase x2, 4blk/CU, fp32-direct, register-direct)
// all regressed in r4-r8; r0's 2-barrier K-loop is the session's empirical
// optimum for this shape (MfmaUtil 27%, stage+drain bound per m233).
// ---------------------------------------------------------------------------

typedef __attribute__((ext_vector_type(8))) short short8;   // 8 bf16 = 4 VGPRs
typedef __attribute__((ext_vector_type(4))) float floatx4;  // MFMA acc

#define AS1(p) ((const __attribute__((address_space(1))) void*)(p))
#define AS3(p) ((__attribute__((address_space(3))) void*)(p))

__device__ __forceinline__ unsigned short f2bf(float f) {
  union { float f; unsigned u; } v; v.f = f;
  unsigned u = v.u;
  return (unsigned short)((u + 0x7fffu + ((u >> 16) & 1u)) >> 16);  // RNE
}

// --------------------------- pack everything -------------------------------
// blocks [0,8192):    A[b][k] = k<512 ? x[b][k] : h[b][k-512]     (8192x1024)
// blocks [8192,10240): B[n][k], n = hh*4 + g (h-interleaved gates f,i,g,o),
//                      k<512 -> Wx else Wh; bias[n] = bx+bh at k==0.
struct PackArgs {
  const float* x; const float* h;
  const float* wx[4]; const float* wh[4];
  const float* bx[4]; const float* bh[4];
  unsigned short* A; unsigned short* B; float* bias;
};

__global__ __launch_bounds__(256) void pack_all_kernel(PackArgs P) {
  const int bid = blockIdx.x;
  if (bid < 8192) {
    int e = (bid * 256 + threadIdx.x) * 4;
    int b = e >> 10, k = e & 1023;
    const float* src = (k < 512) ? (P.x + b * 512 + k)
                                 : (P.h + b * 512 + (k - 512));
    float4 v = *(const float4*)src;
    ushort4 o;
    o.x = f2bf(v.x); o.y = f2bf(v.y); o.z = f2bf(v.z); o.w = f2bf(v.w);
    *(ushort4*)(P.A + e) = o;
  } else {
    int e = ((bid - 8192) * 256 + threadIdx.x) * 4;
    int n = e >> 10, k = e & 1023;
    int g = n & 3, hh = n >> 2;                 // h-interleaved layout
    const float* src = (k < 512) ? (P.wx[g] + hh * 512 + k)
                                 : (P.wh[g] + hh * 512 + (k - 512));
    float4 v = *(const float4*)src;
    ushort4 o;
    o.x = f2bf(v.x); o.y = f2bf(v.y); o.z = f2bf(v.z); o.w = f2bf(v.w);
    *(ushort4*)(P.B + e) = o;
    if (k == 0) P.bias[n] = P.bx[g][hh] + P.bh[g][hh];
  }
}

// --------------------------- fused GEMM + LSTM epilogue --------------------
// Grid (32,16): tile = 256 batch x 128 cols (32 hidden x 4 gates). K=1024,
// BK=64. 512 threads = 8 waves; wave tile 64x64 (4x4 frags of 16x16x32).
// LDS: As 32KB @ [0,32768), Bs 16KB @ [32768,49152); epilogue overlays As.
__global__ __launch_bounds__(512, 4)
void lstm_gemm_kernel(const unsigned short* __restrict__ A,   // [8192][1024]
                      const unsigned short* __restrict__ B,   // [2048][1024]
                      const float* __restrict__ bias,         // [2048]
                      const float* __restrict__ c_prev,       // [8192][512]
                      float* __restrict__ h_out,              // [8192][512]
                      float* __restrict__ c_out) {            // [8192][512]
  __shared__ __align__(16) char smem[49152];
  __shared__ __align__(16) float biasS[128];

  const int tid  = threadIdx.x;
  const int lane = tid & 63;
  const int w    = tid >> 6;        // wave 0..7
  const int quad = lane >> 4;
  const int colA = lane & 15;
  const int m0   = blockIdx.x * 256;
  const int n0   = blockIdx.y * 128;    // = 4*h0
  const int h0   = blockIdx.y * 32;

  if (tid < 128) biasS[tid] = bias[n0 + tid];   // contiguous (h-interleave)

  // staging: thread covers tile-row r = j*64 + (tid>>3), 16B chunk (tid&7);
  // global chunk XOR-swizzled by row&7 so ds_read_b128 frags are conflict-free
  const int srow = tid >> 3;        // 0..63
  const int cl   = tid & 7;
  const int cg   = cl ^ (srow & 7);

  floatx4 acc[4][4];
#pragma unroll
  for (int i = 0; i < 4; ++i)
#pragma unroll
    for (int j = 0; j < 4; ++j) acc[i][j] = (floatx4){0.f, 0.f, 0.f, 0.f};

  const int wm = (w >> 1) * 64;     // wave M offset in tile (0,64,128,192)
  const int wn = (w & 1) * 64;      // wave N offset (0 or 64)

  const char* Ag = (const char*)A;
  const char* Bg = (const char*)B;

  for (int kt = 0; kt < 16; ++kt) {
    __syncthreads();                // prior LDS reads done
    const int kb = kt * 128;        // byte offset into 2048-B rows
#pragma unroll
    for (int j = 0; j < 4; ++j) {   // A: 256 rows
      int r = j * 64 + srow;        // tile row 0..255 (r&7 == srow&7)
      __builtin_amdgcn_global_load_lds(
          AS1(Ag + (size_t)(m0 + r) * 2048 + kb + cg * 16),
          AS3(smem + r * 128 + cl * 16), 16, 0, 0);
    }
#pragma unroll
    for (int j = 0; j < 2; ++j) {   // B: 128 rows (h-interleaved)
      int r = j * 64 + srow;        // tile row 0..127
      __builtin_amdgcn_global_load_lds(
          AS1(Bg + (size_t)(n0 + r) * 2048 + kb + cg * 16),
          AS3(smem + 32768 + r * 128 + cl * 16), 16, 0, 0);
    }
    __syncthreads();                // drains vmcnt(0)

#pragma unroll
    for (int kk = 0; kk < 2; ++kk) {
      const int off = ((kk * 4 + quad) ^ (colA & 7)) * 16;
      short8 af[4], bfr[4];
#pragma unroll
      for (int mi = 0; mi < 4; ++mi)
        af[mi] = *(const short8*)(smem + (wm + mi * 16 + colA) * 128 + off);
#pragma unroll
      for (int ni = 0; ni < 4; ++ni)
        bfr[ni] = *(const short8*)(smem + 32768 + (wn + ni * 16 + colA) * 128 + off);
#pragma unroll
      for (int mi = 0; mi < 4; ++mi)
#pragma unroll
        for (int ni = 0; ni < 4; ++ni)
          acc[mi][ni] = __builtin_amdgcn_mfma_f32_16x16x32_bf16(
              af[mi], bfr[ni], acc[mi][ni], 0, 0, 0);
    }
  }

  // ------------------- fused epilogue (4 rounds of 64 M-rows) --------------
  __syncthreads();
  float* ep = (float*)smem;         // [64][132] padded, overlays As
#pragma unroll
  for (int rd = 0; rd < 4; ++rd) {
    // c_prev hoisted: HBM latency hides under ep writes + barrier
    float cp[4];
#pragma unroll
    for (int j = 0; j < 4; ++j) {
      int idx  = j * 512 + tid;     // 0..2047
      int mloc = idx >> 5;
      int hh   = idx & 31;
      cp[j] = c_prev[(m0 + rd * 64 + mloc) * 512 + h0 + hh];
    }
    if ((w >> 1) == rd) {           // the 2 waves with wm == rd*64
      // C/D layout: row = quad*4 + rr, col = lane&15
#pragma unroll
      for (int mi = 0; mi < 4; ++mi)
#pragma unroll
        for (int ni = 0; ni < 4; ++ni) {
          int rr0 = mi * 16 + quad * 4;                 // 0..63
          int cc  = wn + ni * 16 + colA;                // 0..127
#pragma unroll
          for (int rr = 0; rr < 4; ++rr)
            ep[(rr0 + rr) * 132 + cc] = acc[mi][ni][rr];
        }
    }
    __syncthreads();
#pragma unroll
    for (int j = 0; j < 4; ++j) {
      int idx  = j * 512 + tid;     // 0..2047
      int mloc = idx >> 5;
      int hh   = idx & 31;
      // one aligned float4 = (f,i,g,o) pre-activations for this (m,h)
      float4 pre = *(const float4*)(ep + mloc * 132 + hh * 4);
      float4 bb  = *(const float4*)(biasS + hh * 4);
      float pf = pre.x + bb.x;
      float pi = pre.y + bb.y;
      float pg = pre.z + bb.z;
      float po = pre.w + bb.w;
      float fg = 1.f / (1.f + __expf(-pf));
      float ig = 1.f / (1.f + __expf(-pi));
      float gg = 1.f - 2.f / (1.f + __expf(2.f * pg));
      float og = 1.f / (1.f + __expf(-po));
      float cv = fg * cp[j] + ig * gg;
      float th = 1.f - 2.f / (1.f + __expf(2.f * cv));
      int m  = m0 + rd * 64 + mloc;
      int hg = h0 + hh;
      h_out[m * 512 + hg] = og * th;
      c_out[m * 512 + hg] = cv;
    }
    __syncthreads();
  }
}

// ---------------------------------------------------------------------------
extern "C" void kernel_launch(void* const* d_in, const int* in_sizes, int n_in,
                              void* d_out, int out_size, void* d_ws, size_t ws_size,
                              hipStream_t stream) {
  // workspace: A_bf16 (16 MiB) | B_bf16 (4 MiB) | bias (8 KiB)
  char* ws = (char*)d_ws;
  unsigned short* Abf = (unsigned short*)ws;
  unsigned short* Bbf = (unsigned short*)(ws + (size_t)16777216);
  float* bias = (float*)(ws + (size_t)16777216 + 4194304);

  float* hout = (float*)d_out;
  float* cout = hout + (size_t)8192 * 512;

  PackArgs P;
  P.x = (const float*)d_in[0];
  P.h = (const float*)d_in[1];
  // gate order: 0=f, 1=i, 2=g(cell), 3=o
  P.wx[0] = (const float*)d_in[3];  P.bx[0] = (const float*)d_in[4];
  P.wh[0] = (const float*)d_in[5];  P.bh[0] = (const float*)d_in[6];
  P.wx[1] = (const float*)d_in[7];  P.bx[1] = (const float*)d_in[8];
  P.wh[1] = (const float*)d_in[9];  P.bh[1] = (const float*)d_in[10];
  P.wx[2] = (const float*)d_in[11]; P.bx[2] = (const float*)d_in[12];
  P.wh[2] = (const float*)d_in[13]; P.bh[2] = (const float*)d_in[14];
  P.wx[3] = (const float*)d_in[15]; P.bx[3] = (const float*)d_in[16];
  P.wh[3] = (const float*)d_in[17]; P.bh[3] = (const float*)d_in[18];
  P.A = Abf; P.B = Bbf; P.bias = bias;

  pack_all_kernel<<<10240, 256, 0, stream>>>(P);

  const float* c = (const float*)d_in[2];
  dim3 grid(32, 16);
  lstm_gemm_kernel<<<grid, 512, 0, stream>>>(Abf, Bbf, bias, c, hout, cout);
}